// Round 1
// 276.720 us; speedup vs baseline: 1.0015x; 1.0015x over previous
//
#include <hip/hip_runtime.h>

#define LEVELS 256
#define NROWS 64
#define ROWLEN 786432                    // elements per row
#define CHUNKS 32                        // 2048 blocks x 4 waves = full occupancy
#define CHUNK_ELEMS (ROWLEN / CHUNKS)    // 24576
#define BLOCK 256
#define WAVES (BLOCK / 64)

typedef int   v4i __attribute__((ext_vector_type(4)));
typedef float v4f __attribute__((ext_vector_type(4)));

// Kernel 1: per-(row,chunk) partial histograms, plain stores (no pre-zeroed ws
// needed — every slot fully written). ws: partial[row*CHUNKS+chunk][256] u32 = 2 MB.
// 4 int4 loads in flight per iteration before the atomic burst (MLP).
__global__ __launch_bounds__(256) void hist_partial_kernel(const int* __restrict__ x,
                                                           unsigned int* __restrict__ ws) {
    __shared__ unsigned int lhist[WAVES][LEVELS];   // per-wave private histograms (4 KiB)

    const int row   = blockIdx.y;
    const int chunk = blockIdx.x;
    const int tid   = threadIdx.x;
    const int wave  = tid >> 6;

    unsigned int* flat = &lhist[0][0];
    for (int i = tid; i < WAVES * LEVELS; i += BLOCK) flat[i] = 0u;
    __syncthreads();

    const v4i* xr = (const v4i*)(x + (long)row * ROWLEN + (long)chunk * CHUNK_ELEMS);
    const int n4 = CHUNK_ELEMS / 4;                 // 6144 int4 per block
    unsigned int* h = lhist[wave];
    for (int i = tid; i < n4; i += 4 * BLOCK) {     // 6 iterations
        v4i a = xr[i];
        v4i b = xr[i + BLOCK];
        v4i c = xr[i + 2 * BLOCK];
        v4i d = xr[i + 3 * BLOCK];
        atomicAdd(&h[a.x & 255], 1u);
        atomicAdd(&h[a.y & 255], 1u);
        atomicAdd(&h[a.z & 255], 1u);
        atomicAdd(&h[a.w & 255], 1u);
        atomicAdd(&h[b.x & 255], 1u);
        atomicAdd(&h[b.y & 255], 1u);
        atomicAdd(&h[b.z & 255], 1u);
        atomicAdd(&h[b.w & 255], 1u);
        atomicAdd(&h[c.x & 255], 1u);
        atomicAdd(&h[c.y & 255], 1u);
        atomicAdd(&h[c.z & 255], 1u);
        atomicAdd(&h[c.w & 255], 1u);
        atomicAdd(&h[d.x & 255], 1u);
        atomicAdd(&h[d.y & 255], 1u);
        atomicAdd(&h[d.z & 255], 1u);
        atomicAdd(&h[d.w & 255], 1u);
    }
    __syncthreads();

    // reduce 4 waves -> 256 partial bins, plain coalesced stores (ws stays cached
    // for kernel 2 — no nt here)
    unsigned int* dst = ws + ((long)(row * CHUNKS + chunk)) * LEVELS;
    for (int bin = tid; bin < LEVELS; bin += BLOCK) {
        unsigned int s = 0u;
        #pragma unroll
        for (int w = 0; w < WAVES; ++w) s += lhist[w][bin];
        dst[bin] = s;                                // plain store
    }
}

// Kernel 2: sum the 32 chunk-partials per (row,bin) with COALESCED loads
// (lane -> bin, loop over chunks), then broadcast across the 256-wide last dim.
// Block = (row, bin-octet of 32 bins). Grid = 64*8 = 512 blocks (2 blocks/CU).
// Output stores are NON-TEMPORAL: out is never read, and plain stores would
// evict the L3-resident input between graph replays.
__global__ __launch_bounds__(256) void reduce_broadcast_kernel(const unsigned int* __restrict__ ws,
                                                               float* __restrict__ out) {
    __shared__ unsigned int red[8][32];
    __shared__ float vals[32];

    const int row  = blockIdx.x >> 3;          // 0..63
    const int bq   = blockIdx.x & 7;           // bin octet 0..7
    const int tid  = threadIdx.x;
    const int wave = tid >> 6;
    const int lane = tid & 63;
    const int g    = wave * 2 + (lane >> 5);   // chunk group 0..7
    const int binl = lane & 31;
    const int bin  = bq * 32 + binl;

    // coalesced: consecutive lanes read consecutive bins of the same chunk row
    const unsigned int* base = ws + (long)row * CHUNKS * LEVELS + bin;
    unsigned int s = 0u;
    #pragma unroll
    for (int c = g; c < CHUNKS; c += 8) s += base[(long)c * LEVELS];

    red[g][binl] = s;
    __syncthreads();

    if (tid < 32) {
        unsigned int t = 0u;
        #pragma unroll
        for (int gg = 0; gg < 8; ++gg) t += red[gg][tid];
        vals[tid] = (float)t;
    }
    __syncthreads();

    // out[row][bq*32 .. bq*32+31][0..255] : 32 KB contiguous, float4/lane, nt stores
    v4f* dst = (v4f*)(out + ((long)row * LEVELS + bq * 32) * LEVELS);
    #pragma unroll
    for (int i = tid; i < 32 * (LEVELS / 4); i += BLOCK) {   // 8 iterations
        float v = vals[i >> 6];                              // wave-uniform -> LDS broadcast
        v4f f = {v, v, v, v};
        __builtin_nontemporal_store(f, &dst[i]);
    }
}

extern "C" void kernel_launch(void* const* d_in, const int* in_sizes, int n_in,
                              void* d_out, int out_size, void* d_ws, size_t ws_size,
                              hipStream_t stream) {
    const int* x = (const int*)d_in[0];
    float* out = (float*)d_out;
    unsigned int* ws = (unsigned int*)d_ws;    // 2 MB of partials, fully overwritten

    dim3 grid(CHUNKS, NROWS);
    hist_partial_kernel<<<grid, BLOCK, 0, stream>>>(x, ws);

    reduce_broadcast_kernel<<<NROWS * 8, BLOCK, 0, stream>>>(ws, out);
}